// Round 1
// baseline (562.323 us; speedup 1.0000x reference)
//
#include <hip/hip_runtime.h>
#include <math.h>

#define B_    32
#define S_    4096
#define DIN_  256
#define D_    256
#define T_    256
#define NB_   4
#define K_    5
#define EPS_  1e-5f
#define ROWS_ (B_ * T_)   // 8192

// ---------------------------------------------------------------------------
// Kernel 1: lengths[b] = sum(mask[b, :]) with runtime dtype detection.
// The reference mask is bool; the harness may hand it to us as int32 (doc
// says "integer -> const int*"), uint8, or float32. Detect:
//   word0 == 0x3F800000            -> float32 (mask[0][0] is always True)
//   any of 32 probe words > 1      -> uint8 (packed 0x01 bytes)
//   else                           -> int32
// ---------------------------------------------------------------------------
__global__ void k_lengths(const unsigned int* __restrict__ mask_w, int* __restrict__ lengths) {
    int b = blockIdx.x;
    int tid = threadIdx.x;

    // mode detection (each block does it independently; 33 scalar loads)
    int mode = 0; // 0=int32, 1=uint8, 2=float32
    unsigned int w0 = mask_w[0];
    if (w0 == 0x3F800000u) {
        mode = 2;
    } else {
        bool u8 = false;
        for (int i = 0; i < 32; ++i) {
            unsigned int w = mask_w[i * 1024];
            if (w > 1u) { u8 = true; break; }
        }
        mode = u8 ? 1 : 0;
    }

    int s = 0;
    if (mode == 0) {
        const int* m = (const int*)mask_w;
        for (int i = tid; i < S_; i += 256) s += (m[(size_t)b * S_ + i] != 0);
    } else if (mode == 2) {
        const float* m = (const float*)mask_w;
        for (int i = tid; i < S_; i += 256) s += (m[(size_t)b * S_ + i] != 0.0f);
    } else {
        const unsigned char* m = (const unsigned char*)mask_w;
        for (int i = tid; i < S_; i += 256) s += (m[(size_t)b * S_ + i] != 0);
    }

    __shared__ int sm[256];
    sm[tid] = s;
    __syncthreads();
    for (int off = 128; off > 0; off >>= 1) {
        if (tid < off) sm[tid] += sm[tid + off];
        __syncthreads();
    }
    if (tid == 0) lengths[b] = sm[0];
}

// ---------------------------------------------------------------------------
// Kernel 2: compress — linear interp of valid prefix to T=256 rows.
// One block per (b,t); thread = channel d.
// ---------------------------------------------------------------------------
__global__ void k_compress(const float* __restrict__ x, const int* __restrict__ lengths,
                           float* __restrict__ xc) {
    int bt = blockIdx.x;
    int b = bt >> 8;       // / T_
    int t = bt & (T_ - 1);
    int L = lengths[b];
    float Lf = (float)L;
    float src = ((float)t + 0.5f) * (Lf / (float)T_) - 0.5f;
    float hi = fmaxf(Lf - 1.0f, 0.0f);
    src = fminf(fmaxf(src, 0.0f), hi);
    int i0 = (int)floorf(src);
    int i1 = min(i0 + 1, max(L - 1, 0));
    float w = src - (float)i0;
    int d = threadIdx.x;
    float v0 = x[((size_t)b * S_ + i0) * DIN_ + d];
    float v1 = x[((size_t)b * S_ + i1) * DIN_ + d];
    xc[(size_t)bt * DIN_ + d] = (1.0f - w) * v0 + w * v1;
}

// ---------------------------------------------------------------------------
// Kernel 3: tiled fp32 GEMM. C[M,N] = A[M,K] @ W[K,N] + bias[N] (+ Cin).
// BM=64 BN=64 BK=16, 256 threads, 4x4 microtile.
// ---------------------------------------------------------------------------
template<int BM, int BN, int BK, int TM, int TN>
__global__ __launch_bounds__(256) void k_gemm(
    const float* __restrict__ A, const float* __restrict__ W,
    const float* __restrict__ bias, const float* __restrict__ Cin,
    float* __restrict__ C, int M, int N, int K) {
    __shared__ __align__(16) float As[BK][BM];
    __shared__ __align__(16) float Bs[BK][BN];
    int tid = threadIdx.x;
    int bm = blockIdx.y * BM;
    int bn = blockIdx.x * BN;
    int tcol = tid % (BN / TN);  // 0..15
    int trow = tid / (BN / TN);  // 0..15
    float acc[TM][TN] = {};

    for (int k0 = 0; k0 < K; k0 += BK) {
        // A tile: BM x BK = 1024 floats -> 256 float4 loads (one per thread)
        {
            int r  = tid / (BK / 4);        // 0..63
            int c4 = (tid % (BK / 4)) * 4;  // 0,4,8,12
            float4 v = *(const float4*)&A[(size_t)(bm + r) * K + k0 + c4];
            As[c4 + 0][r] = v.x;
            As[c4 + 1][r] = v.y;
            As[c4 + 2][r] = v.z;
            As[c4 + 3][r] = v.w;
        }
        // B tile: BK x BN = 1024 floats -> 256 float4 loads
        {
            int rb = tid / (BN / 4);        // 0..15
            int cb = (tid % (BN / 4)) * 4;
            float4 wv = *(const float4*)&W[(size_t)(k0 + rb) * N + bn + cb];
            *(float4*)&Bs[rb][cb] = wv;
        }
        __syncthreads();
#pragma unroll
        for (int k = 0; k < BK; ++k) {
            float4 am = *(const float4*)&As[k][trow * TM];
            float4 bv = *(const float4*)&Bs[k][tcol * TN];
            float amv[TM] = {am.x, am.y, am.z, am.w};
            float bnv[TN] = {bv.x, bv.y, bv.z, bv.w};
#pragma unroll
            for (int i = 0; i < TM; ++i)
#pragma unroll
                for (int j = 0; j < TN; ++j) acc[i][j] += amv[i] * bnv[j];
        }
        __syncthreads();
    }

#pragma unroll
    for (int i = 0; i < TM; ++i) {
        int r = bm + trow * TM + i;
        int c = bn + tcol * TN;
        float4 bv = *(const float4*)&bias[c];
        float4 o;
        o.x = acc[i][0] + bv.x;
        o.y = acc[i][1] + bv.y;
        o.z = acc[i][2] + bv.z;
        o.w = acc[i][3] + bv.w;
        if (Cin) {
            float4 ci = *(const float4*)&Cin[(size_t)r * N + c];
            o.x += ci.x; o.y += ci.y; o.z += ci.z; o.w += ci.w;
        }
        *(float4*)&C[(size_t)r * N + c] = o;
    }
}

// ---------------------------------------------------------------------------
// Kernel 4: per-row LN stats (mu, rsig). One wave per row, 4 rows per block.
// ---------------------------------------------------------------------------
__global__ void k_lnstats(const float* __restrict__ h, float2* __restrict__ stats) {
    int wave = threadIdx.x >> 6;
    int lane = threadIdx.x & 63;
    int row = blockIdx.x * 4 + wave;
    const float* p = h + (size_t)row * D_;
    float s = 0.f, ss = 0.f;
#pragma unroll
    for (int i = 0; i < 4; ++i) {
        float v = p[lane + i * 64];
        s += v;
        ss += v * v;
    }
#pragma unroll
    for (int off = 1; off < 64; off <<= 1) {
        s += __shfl_xor(s, off);
        ss += __shfl_xor(ss, off);
    }
    if (lane == 0) {
        float mu = s * (1.0f / D_);
        float var = ss * (1.0f / D_) - mu * mu;
        stats[row] = make_float2(mu, rsqrtf(var + EPS_));
    }
}

// ---------------------------------------------------------------------------
// Kernel 5: depthwise conv (K=5, pad 2) over LN'd h, using precomputed stats.
// hc[b,t,d] = sum_k LN(h)[b,t+k-2,d] * w[d,k] + wb[d]
// ---------------------------------------------------------------------------
__global__ void k_dwconv(const float* __restrict__ h, const float2* __restrict__ stats,
                         const float* __restrict__ g, const float* __restrict__ bta,
                         const float* __restrict__ w, const float* __restrict__ wb,
                         float* __restrict__ hc) {
    int idx = blockIdx.x * 256 + threadIdx.x;
    if (idx >= ROWS_ * D_) return;
    int d = idx & (D_ - 1);
    int bt = idx >> 8;
    int t = bt & (T_ - 1);
    int b = bt >> 8;
    float gg = g[d], bb = bta[d];
    float acc = wb[d];
#pragma unroll
    for (int k = 0; k < K_; ++k) {
        int tt = t + k - 2;
        if (tt >= 0 && tt < T_) {
            int r = b * T_ + tt;
            float2 st = stats[r];
            float hn = (h[(size_t)r * D_ + d] - st.x) * st.y * gg + bb;
            acc += hn * w[d * K_ + k];
        }
    }
    hc[idx] = acc;
}

// ---------------------------------------------------------------------------
// Kernel 6: gated activation. act = sigmoid(gate) * gelu_exact(val)
// gate = gv[:, :256], val = gv[:, 256:512]
// ---------------------------------------------------------------------------
__global__ void k_act(const float* __restrict__ gv, float* __restrict__ act) {
    int idx = blockIdx.x * 256 + threadIdx.x;
    if (idx >= ROWS_ * D_) return;
    int r = idx >> 8;
    int c = idx & (D_ - 1);
    float gate = gv[(size_t)r * 512 + c];
    float val = gv[(size_t)r * 512 + c + 256];
    float sg = 1.0f / (1.0f + expf(-gate));
    float ge = 0.5f * val * (1.0f + erff(val * 0.70710678118654752f));
    act[idx] = sg * ge;
}

// ---------------------------------------------------------------------------
// Kernel 7: final LayerNorm -> out. One wave per row.
// ---------------------------------------------------------------------------
__global__ void k_final_ln(const float* __restrict__ h, const float* __restrict__ g,
                           const float* __restrict__ b, float* __restrict__ out) {
    int wave = threadIdx.x >> 6;
    int lane = threadIdx.x & 63;
    int row = blockIdx.x * 4 + wave;
    const float* p = h + (size_t)row * D_;
    float v[4];
    float s = 0.f, ss = 0.f;
#pragma unroll
    for (int i = 0; i < 4; ++i) {
        v[i] = p[lane + i * 64];
        s += v[i];
        ss += v[i] * v[i];
    }
#pragma unroll
    for (int off = 1; off < 64; off <<= 1) {
        s += __shfl_xor(s, off);
        ss += __shfl_xor(ss, off);
    }
    float mu = s * (1.0f / D_);
    float rsig = rsqrtf(ss * (1.0f / D_) - mu * mu + EPS_);
#pragma unroll
    for (int i = 0; i < 4; ++i) {
        int d = lane + i * 64;
        out[(size_t)row * D_ + d] = (v[i] - mu) * rsig * g[d] + b[d];
    }
}

// Kernel 8: comp_mask output (always true since lengths >= 1) -> 1.0f
__global__ void k_mask(float* __restrict__ om) {
    int i = blockIdx.x * 256 + threadIdx.x;
    if (i < ROWS_) om[i] = 1.0f;
}

// ---------------------------------------------------------------------------
extern "C" void kernel_launch(void* const* d_in, const int* in_sizes, int n_in,
                              void* d_out, int out_size, void* d_ws, size_t ws_size,
                              hipStream_t stream) {
    const float* x      = (const float*)d_in[0];
    const unsigned int* mask_w = (const unsigned int*)d_in[1];
    const float* in_w   = (const float*)d_in[2];
    const float* in_b   = (const float*)d_in[3];
    const float* ln_g   = (const float*)d_in[4];
    const float* ln_b   = (const float*)d_in[5];
    const float* dw_w   = (const float*)d_in[6];
    const float* dw_b   = (const float*)d_in[7];
    const float* win_w  = (const float*)d_in[8];
    const float* win_b  = (const float*)d_in[9];
    const float* wout_w = (const float*)d_in[10];
    const float* wout_b = (const float*)d_in[11];
    const float* fn_g   = (const float*)d_in[12];
    const float* fn_b   = (const float*)d_in[13];

    char* w8 = (char*)d_ws;
    int*    lengths = (int*)w8;                          // 128 B
    float2* stats   = (float2*)(w8 + 256);               // 64 KB
    float*  h       = (float*)(w8 + 256 + 65536);        // 8 MB
    float*  tmp     = h + (size_t)ROWS_ * D_;            // 8 MB (xc / hc / act)
    float*  gv      = tmp + (size_t)ROWS_ * D_;          // 16 MB

    float* out0 = (float*)d_out;
    float* out1 = out0 + (size_t)ROWS_ * D_;

    // 1. lengths
    k_lengths<<<B_, 256, 0, stream>>>(mask_w, lengths);
    // 2. compress -> tmp (xc)
    k_compress<<<ROWS_, 256, 0, stream>>>(x, lengths, tmp);
    // 3. h = xc @ in_w + in_b
    k_gemm<64, 64, 16, 4, 4><<<dim3(D_ / 64, ROWS_ / 64), 256, 0, stream>>>(
        tmp, in_w, in_b, nullptr, h, ROWS_, D_, DIN_);

    for (int i = 0; i < NB_; ++i) {
        const float* g_i   = ln_g + i * D_;
        const float* b_i   = ln_b + i * D_;
        const float* dww_i = dw_w + i * D_ * K_;
        const float* dwb_i = dw_b + i * D_;
        const float* ww_i  = win_w + (size_t)i * D_ * 2 * D_;
        const float* wb_i  = win_b + i * 2 * D_;
        const float* ow_i  = wout_w + (size_t)i * D_ * D_;
        const float* ob_i  = wout_b + i * D_;

        k_lnstats<<<ROWS_ / 4, 256, 0, stream>>>(h, stats);
        k_dwconv<<<ROWS_ * D_ / 256, 256, 0, stream>>>(h, stats, g_i, b_i, dww_i, dwb_i, tmp);
        k_gemm<64, 64, 16, 4, 4><<<dim3(2 * D_ / 64, ROWS_ / 64), 256, 0, stream>>>(
            tmp, ww_i, wb_i, nullptr, gv, ROWS_, 2 * D_, D_);
        k_act<<<ROWS_ * D_ / 256, 256, 0, stream>>>(gv, tmp);
        // h = h + act @ wout + wout_b
        k_gemm<64, 64, 16, 4, 4><<<dim3(D_ / 64, ROWS_ / 64), 256, 0, stream>>>(
            tmp, ow_i, ob_i, h, h, ROWS_, D_, D_);
    }

    k_final_ln<<<ROWS_ / 4, 256, 0, stream>>>(h, fn_g, fn_b, out0);
    k_mask<<<(ROWS_ + 255) / 256, 256, 0, stream>>>(out1);
}

// Round 2
// 413.047 us; speedup vs baseline: 1.3614x; 1.3614x over previous
//
#include <hip/hip_runtime.h>
#include <math.h>

#define B_    32
#define S_    4096
#define DIN_  256
#define D_    256
#define T_    256
#define NB_   4
#define K_    5
#define EPS_  1e-5f
#define ROWS_ (B_ * T_)   // 8192

typedef short  shortx8 __attribute__((ext_vector_type(8)));
typedef float  floatx4 __attribute__((ext_vector_type(4)));
typedef unsigned short ushortx8 __attribute__((ext_vector_type(8)));

// fp32 -> bf16 round-to-nearest-even
__device__ __forceinline__ unsigned short f2bf(float f) {
    unsigned int u = __float_as_uint(f);
    u += 0x7FFFu + ((u >> 16) & 1u);
    return (unsigned short)(u >> 16);
}

// ---------------------------------------------------------------------------
// Kernel 1: lengths[b] = sum(mask[b,:]) with runtime dtype detection
// (int32 / uint8 / float32 — see R0 notes; passed as-is in R1).
// ---------------------------------------------------------------------------
__global__ void k_lengths(const unsigned int* __restrict__ mask_w, int* __restrict__ lengths) {
    int b = blockIdx.x;
    int tid = threadIdx.x;
    int mode = 0; // 0=int32, 1=uint8, 2=float32
    unsigned int w0 = mask_w[0];
    if (w0 == 0x3F800000u) {
        mode = 2;
    } else {
        bool u8 = false;
        for (int i = 0; i < 32; ++i) {
            unsigned int w = mask_w[i * 1024];
            if (w > 1u) { u8 = true; break; }
        }
        mode = u8 ? 1 : 0;
    }
    int s = 0;
    if (mode == 0) {
        const int* m = (const int*)mask_w;
        for (int i = tid; i < S_; i += 256) s += (m[(size_t)b * S_ + i] != 0);
    } else if (mode == 2) {
        const float* m = (const float*)mask_w;
        for (int i = tid; i < S_; i += 256) s += (m[(size_t)b * S_ + i] != 0.0f);
    } else {
        const unsigned char* m = (const unsigned char*)mask_w;
        for (int i = tid; i < S_; i += 256) s += (m[(size_t)b * S_ + i] != 0);
    }
    __shared__ int sm[256];
    sm[tid] = s;
    __syncthreads();
    for (int off = 128; off > 0; off >>= 1) {
        if (tid < off) sm[tid] += sm[tid + off];
        __syncthreads();
    }
    if (tid == 0) lengths[b] = sm[0];
}

// ---------------------------------------------------------------------------
// Kernel 2: compress -> bf16 A-matrix [ROWS, DIN]
// ---------------------------------------------------------------------------
__global__ void k_compress(const float* __restrict__ x, const int* __restrict__ lengths,
                           unsigned short* __restrict__ xc) {
    int bt = blockIdx.x;
    int b = bt >> 8;
    int t = bt & (T_ - 1);
    int L = lengths[b];
    float Lf = (float)L;
    float src = ((float)t + 0.5f) * (Lf / (float)T_) - 0.5f;
    float hi = fmaxf(Lf - 1.0f, 0.0f);
    src = fminf(fmaxf(src, 0.0f), hi);
    int i0 = (int)floorf(src);
    int i1 = min(i0 + 1, max(L - 1, 0));
    float w = src - (float)i0;
    int d = threadIdx.x;
    float v0 = x[((size_t)b * S_ + i0) * DIN_ + d];
    float v1 = x[((size_t)b * S_ + i1) * DIN_ + d];
    xc[(size_t)bt * DIN_ + d] = f2bf((1.0f - w) * v0 + w * v1);
}

// ---------------------------------------------------------------------------
// Kernel 3: weight transpose+convert: src [K][N] fp32 -> dst [N][K] bf16.
// blockIdx.z selects matrix: 0=in_w, 1..4=win_w[i], 5..8=wout_w[i].
// ---------------------------------------------------------------------------
__global__ void k_wt(const float* __restrict__ in_w, const float* __restrict__ win_w,
                     const float* __restrict__ wout_w,
                     unsigned short* __restrict__ wt_in, unsigned short* __restrict__ wt_win,
                     unsigned short* __restrict__ wt_wout) {
    int z = blockIdx.z;
    const float* src; unsigned short* dst; int N, Kd;
    if (z == 0)      { src = in_w;                              dst = wt_in;                          N = D_;     Kd = DIN_; }
    else if (z <= 4) { src = win_w  + (size_t)(z - 1) * D_ * 2 * D_; dst = wt_win  + (size_t)(z - 1) * 2 * D_ * D_; N = 2 * D_; Kd = D_; }
    else             { src = wout_w + (size_t)(z - 5) * D_ * D_;     dst = wt_wout + (size_t)(z - 5) * D_ * D_;     N = D_;     Kd = D_; }
    int bx = blockIdx.x * 32;   // N offset
    int by = blockIdx.y * 32;   // K offset
    if (bx >= N) return;
    __shared__ float tile[32][33];
    int tx = threadIdx.x & 31, ty = threadIdx.x >> 5;  // 32x8
#pragma unroll
    for (int i = 0; i < 32; i += 8)
        tile[ty + i][tx] = src[(size_t)(by + ty + i) * N + bx + tx];
    __syncthreads();
#pragma unroll
    for (int i = 0; i < 32; i += 8)
        dst[(size_t)(bx + ty + i) * Kd + by + tx] = f2bf(tile[tx][ty + i]);
}

// ---------------------------------------------------------------------------
// Kernel 4: bf16 MFMA GEMM. C[M,N] = A[M,K] @ Wt[N,K]^T + bias (+ Cin), fp32 out.
// 64x64 tile, 256 threads = 4 waves in 2x2, 16x16x32 bf16 MFMA, BK=32.
// ---------------------------------------------------------------------------
__global__ __launch_bounds__(256) void k_gemm_bf16(
    const unsigned short* __restrict__ A, const unsigned short* __restrict__ Wt,
    const float* __restrict__ bias, const float* __restrict__ Cin,
    float* __restrict__ C, int M, int N, int K) {
    __shared__ __align__(16) unsigned short As[64][40];  // [m][k], 8-elem pad
    __shared__ __align__(16) unsigned short Bs[64][40];  // [n][k]
    int tid = threadIdx.x;
    int wave = tid >> 6, lane = tid & 63;
    int wm = (wave >> 1) * 32, wn = (wave & 1) * 32;
    int bm = blockIdx.y * 64, bn = blockIdx.x * 64;

    floatx4 acc[2][2] = {};
    int ar = tid >> 2;          // 0..63 staging row
    int ac = (tid & 3) * 8;     // 0,8,16,24 staging k-offset

    int fm = lane & 15;
    int fk = (lane >> 4) * 8;

    for (int k0 = 0; k0 < K; k0 += 32) {
        *(ushortx8*)&As[ar][ac] = *(const ushortx8*)&A[(size_t)(bm + ar) * K + k0 + ac];
        *(ushortx8*)&Bs[ar][ac] = *(const ushortx8*)&Wt[(size_t)(bn + ar) * K + k0 + ac];
        __syncthreads();
        shortx8 a0 = *(const shortx8*)&As[wm + fm][fk];
        shortx8 a1 = *(const shortx8*)&As[wm + 16 + fm][fk];
        shortx8 b0 = *(const shortx8*)&Bs[wn + fm][fk];
        shortx8 b1 = *(const shortx8*)&Bs[wn + 16 + fm][fk];
        acc[0][0] = __builtin_amdgcn_mfma_f32_16x16x32_bf16(a0, b0, acc[0][0], 0, 0, 0);
        acc[0][1] = __builtin_amdgcn_mfma_f32_16x16x32_bf16(a0, b1, acc[0][1], 0, 0, 0);
        acc[1][0] = __builtin_amdgcn_mfma_f32_16x16x32_bf16(a1, b0, acc[1][0], 0, 0, 0);
        acc[1][1] = __builtin_amdgcn_mfma_f32_16x16x32_bf16(a1, b1, acc[1][1], 0, 0, 0);
        __syncthreads();
    }

    int col = lane & 15;
    int q4 = (lane >> 4) * 4;
#pragma unroll
    for (int i = 0; i < 2; ++i) {
#pragma unroll
        for (int j = 0; j < 2; ++j) {
            int n = bn + wn + j * 16 + col;
            float bv = bias[n];
#pragma unroll
            for (int r = 0; r < 4; ++r) {
                int m = bm + wm + i * 16 + q4 + r;
                float v = acc[i][j][r] + bv;
                if (Cin) v += Cin[(size_t)m * N + n];
                C[(size_t)m * N + n] = v;
            }
        }
    }
}

// ---------------------------------------------------------------------------
// Kernel 5: per-row LN stats. One wave per row, 4 rows/block.
// ---------------------------------------------------------------------------
__global__ void k_lnstats(const float* __restrict__ h, float2* __restrict__ stats) {
    int wave = threadIdx.x >> 6;
    int lane = threadIdx.x & 63;
    int row = blockIdx.x * 4 + wave;
    const float* p = h + (size_t)row * D_;
    float s = 0.f, ss = 0.f;
#pragma unroll
    for (int i = 0; i < 4; ++i) {
        float v = p[lane + i * 64];
        s += v; ss += v * v;
    }
#pragma unroll
    for (int off = 1; off < 64; off <<= 1) {
        s += __shfl_xor(s, off);
        ss += __shfl_xor(ss, off);
    }
    if (lane == 0) {
        float mu = s * (1.0f / D_);
        float var = ss * (1.0f / D_) - mu * mu;
        stats[row] = make_float2(mu, rsqrtf(var + EPS_));
    }
}

// ---------------------------------------------------------------------------
// Kernel 6: depthwise conv (K=5) over LN'd h -> bf16 hc.
// ---------------------------------------------------------------------------
__global__ void k_dwconv(const float* __restrict__ h, const float2* __restrict__ stats,
                         const float* __restrict__ g, const float* __restrict__ bta,
                         const float* __restrict__ w, const float* __restrict__ wb,
                         unsigned short* __restrict__ hc) {
    int idx = blockIdx.x * 256 + threadIdx.x;
    if (idx >= ROWS_ * D_) return;
    int d = idx & (D_ - 1);
    int bt = idx >> 8;
    int t = bt & (T_ - 1);
    int b = bt >> 8;
    float gg = g[d], bb = bta[d];
    float acc = wb[d];
#pragma unroll
    for (int k = 0; k < K_; ++k) {
        int tt = t + k - 2;
        if (tt >= 0 && tt < T_) {
            int r = b * T_ + tt;
            float2 st = stats[r];
            float hn = (h[(size_t)r * D_ + d] - st.x) * st.y * gg + bb;
            acc += hn * w[d * K_ + k];
        }
    }
    hc[idx] = f2bf(acc);
}

// ---------------------------------------------------------------------------
// Kernel 7: gated activation -> bf16. act = sigmoid(gate) * gelu_exact(val)
// ---------------------------------------------------------------------------
__global__ void k_act(const float* __restrict__ gv, unsigned short* __restrict__ act) {
    int idx = blockIdx.x * 256 + threadIdx.x;
    if (idx >= ROWS_ * D_) return;
    int r = idx >> 8;
    int c = idx & (D_ - 1);
    float gate = gv[(size_t)r * 512 + c];
    float val = gv[(size_t)r * 512 + c + 256];
    float sg = 1.0f / (1.0f + expf(-gate));
    float ge = 0.5f * val * (1.0f + erff(val * 0.70710678118654752f));
    act[idx] = f2bf(sg * ge);
}

// ---------------------------------------------------------------------------
// Kernel 8: final LayerNorm -> out.
// ---------------------------------------------------------------------------
__global__ void k_final_ln(const float* __restrict__ h, const float* __restrict__ g,
                           const float* __restrict__ b, float* __restrict__ out) {
    int wave = threadIdx.x >> 6;
    int lane = threadIdx.x & 63;
    int row = blockIdx.x * 4 + wave;
    const float* p = h + (size_t)row * D_;
    float v[4];
    float s = 0.f, ss = 0.f;
#pragma unroll
    for (int i = 0; i < 4; ++i) {
        v[i] = p[lane + i * 64];
        s += v[i]; ss += v[i] * v[i];
    }
#pragma unroll
    for (int off = 1; off < 64; off <<= 1) {
        s += __shfl_xor(s, off);
        ss += __shfl_xor(ss, off);
    }
    float mu = s * (1.0f / D_);
    float rsig = rsqrtf(ss * (1.0f / D_) - mu * mu + EPS_);
#pragma unroll
    for (int i = 0; i < 4; ++i) {
        int d = lane + i * 64;
        out[(size_t)row * D_ + d] = (v[i] - mu) * rsig * g[d] + b[d];
    }
}

__global__ void k_mask(float* __restrict__ om) {
    int i = blockIdx.x * 256 + threadIdx.x;
    if (i < ROWS_) om[i] = 1.0f;
}

// ---------------------------------------------------------------------------
extern "C" void kernel_launch(void* const* d_in, const int* in_sizes, int n_in,
                              void* d_out, int out_size, void* d_ws, size_t ws_size,
                              hipStream_t stream) {
    const float* x      = (const float*)d_in[0];
    const unsigned int* mask_w = (const unsigned int*)d_in[1];
    const float* in_w   = (const float*)d_in[2];
    const float* in_b   = (const float*)d_in[3];
    const float* ln_g   = (const float*)d_in[4];
    const float* ln_b   = (const float*)d_in[5];
    const float* dw_w   = (const float*)d_in[6];
    const float* dw_b   = (const float*)d_in[7];
    const float* win_w  = (const float*)d_in[8];
    const float* win_b  = (const float*)d_in[9];
    const float* wout_w = (const float*)d_in[10];
    const float* wout_b = (const float*)d_in[11];
    const float* fn_g   = (const float*)d_in[12];
    const float* fn_b   = (const float*)d_in[13];

    char* w8 = (char*)d_ws;
    int*    lengths = (int*)w8;                             // @0
    float2* stats   = (float2*)(w8 + 4096);                 // 64 KB
    unsigned short* wt_in   = (unsigned short*)(w8 + (1u << 20));            // 128 KB
    unsigned short* wt_win  = wt_in  + (size_t)D_ * DIN_;                    // 1 MB (4x 512x256)
    unsigned short* wt_wout = wt_win + (size_t)NB_ * 2 * D_ * D_;            // 512 KB
    unsigned short* abuf = (unsigned short*)(w8 + (4u << 20));               // 4 MB bf16 A
    float* h  = (float*)(w8 + (8u << 20));                                   // 8 MB
    float* gv = (float*)(w8 + (16u << 20));                                  // 16 MB

    float* out0 = (float*)d_out;
    float* out1 = out0 + (size_t)ROWS_ * D_;

    k_lengths<<<B_, 256, 0, stream>>>(mask_w, lengths);
    k_wt<<<dim3(16, 8, 9), 256, 0, stream>>>(in_w, win_w, wout_w, wt_in, wt_win, wt_wout);
    k_compress<<<ROWS_, 256, 0, stream>>>(x, lengths, abuf);
    // h = xc @ in_w + in_b
    k_gemm_bf16<<<dim3(D_ / 64, ROWS_ / 64), 256, 0, stream>>>(
        abuf, wt_in, in_b, nullptr, h, ROWS_, D_, DIN_);

    for (int i = 0; i < NB_; ++i) {
        const float* g_i   = ln_g + i * D_;
        const float* b_i   = ln_b + i * D_;
        const float* dww_i = dw_w + i * D_ * K_;
        const float* dwb_i = dw_b + i * D_;
        const unsigned short* ww_i = wt_win + (size_t)i * 2 * D_ * D_;
        const float* wb_i  = win_b + i * 2 * D_;
        const unsigned short* ow_i = wt_wout + (size_t)i * D_ * D_;
        const float* ob_i  = wout_b + i * D_;

        k_lnstats<<<ROWS_ / 4, 256, 0, stream>>>(h, stats);
        k_dwconv<<<ROWS_ * D_ / 256, 256, 0, stream>>>(h, stats, g_i, b_i, dww_i, dwb_i, abuf);
        k_gemm_bf16<<<dim3(2 * D_ / 64, ROWS_ / 64), 256, 0, stream>>>(
            abuf, ww_i, wb_i, nullptr, gv, ROWS_, 2 * D_, D_);
        k_act<<<ROWS_ * D_ / 256, 256, 0, stream>>>(gv, abuf);
        // h = h + act @ wout + wout_b
        k_gemm_bf16<<<dim3(D_ / 64, ROWS_ / 64), 256, 0, stream>>>(
            abuf, ow_i, ob_i, h, h, ROWS_, D_, D_);
    }

    k_final_ln<<<ROWS_ / 4, 256, 0, stream>>>(h, fn_g, fn_b, out0);
    k_mask<<<(ROWS_ + 255) / 256, 256, 0, stream>>>(out1);
}

// Round 3
// 292.458 us; speedup vs baseline: 1.9228x; 1.4123x over previous
//
#include <hip/hip_runtime.h>
#include <math.h>

#define B_    32
#define S_    4096
#define DIN_  256
#define D_    256
#define T_    256
#define NB_   4
#define K_    5
#define EPS_  1e-5f
#define ROWS_ (B_ * T_)   // 8192

#define MROWS 48          // 32 output rows + 8 halo each side
#define ASTR  264         // bf16 row stride (16B-aligned, padded)

typedef short  shortx8 __attribute__((ext_vector_type(8)));
typedef float  floatx4 __attribute__((ext_vector_type(4)));

__device__ __forceinline__ unsigned short f2bf(float f) {
    unsigned int u = __float_as_uint(f);
    u += 0x7FFFu + ((u >> 16) & 1u);
    return (unsigned short)(u >> 16);
}
__device__ __forceinline__ float bf2f(unsigned short h) {
    return __uint_as_float(((unsigned int)h) << 16);
}

// ---------------------------------------------------------------------------
// Weight transpose+convert: src [K][N] fp32 -> dst [N][K] bf16.
// z: 0=in_w, 1..4=win_w[i], 5..8=wout_w[i].  (unchanged from R2, validated)
// ---------------------------------------------------------------------------
__global__ void k_wt(const float* __restrict__ in_w, const float* __restrict__ win_w,
                     const float* __restrict__ wout_w,
                     unsigned short* __restrict__ wt_in, unsigned short* __restrict__ wt_win,
                     unsigned short* __restrict__ wt_wout) {
    int z = blockIdx.z;
    const float* src; unsigned short* dst; int N, Kd;
    if (z == 0)      { src = in_w;                                   dst = wt_in;                                   N = D_;     Kd = DIN_; }
    else if (z <= 4) { src = win_w  + (size_t)(z - 1) * D_ * 2 * D_; dst = wt_win  + (size_t)(z - 1) * 2 * D_ * D_; N = 2 * D_; Kd = D_; }
    else             { src = wout_w + (size_t)(z - 5) * D_ * D_;     dst = wt_wout + (size_t)(z - 5) * D_ * D_;     N = D_;     Kd = D_; }
    int bx = blockIdx.x * 32;
    int by = blockIdx.y * 32;
    if (bx >= N) return;
    __shared__ float tile[32][33];
    int tx = threadIdx.x & 31, ty = threadIdx.x >> 5;
#pragma unroll
    for (int i = 0; i < 32; i += 8)
        tile[ty + i][tx] = src[(size_t)(by + ty + i) * N + bx + tx];
    __syncthreads();
#pragma unroll
    for (int i = 0; i < 32; i += 8)
        dst[(size_t)(bx + ty + i) * Kd + by + tx] = f2bf(tile[tx][ty + i]);
}

// ---------------------------------------------------------------------------
// GEMM helper: C[48 x 256] = A(bf16, LDS) @ W(bf16 [256][256])^T + bias,
// result into hreg (MFMA C-layout ownership). INIT: assign, else +=.
// Wave w owns n-tiles {w, w+8}; 3 m-tiles; 8 k-steps of 32.
// ---------------------------------------------------------------------------
template<bool INIT>
__device__ __forceinline__ void gemm_nk16(
    const unsigned short (*A)[ASTR], const unsigned short* __restrict__ wt,
    const float* __restrict__ bias, float (&hreg)[2][3][4],
    int w, int c16, int q)
{
#pragma unroll
    for (int nn = 0; nn < 2; ++nn) {
        int nt = w + nn * 8;
        const unsigned short* wp = wt + (size_t)(nt * 16 + c16) * 256 + q * 8;
        floatx4 acc[3] = {};
        shortx8 bcur = *(const shortx8*)wp;
#pragma unroll
        for (int kk = 0; kk < 8; ++kk) {
            shortx8 bnext = bcur;
            if (kk < 7) bnext = *(const shortx8*)(wp + (kk + 1) * 32);
#pragma unroll
            for (int mt = 0; mt < 3; ++mt) {
                shortx8 a = *(const shortx8*)&A[mt * 16 + c16][kk * 32 + q * 8];
                acc[mt] = __builtin_amdgcn_mfma_f32_16x16x32_bf16(a, bcur, acc[mt], 0, 0, 0);
            }
            bcur = bnext;
        }
        float ob = bias[nt * 16 + c16];
#pragma unroll
        for (int mt = 0; mt < 3; ++mt)
#pragma unroll
            for (int r = 0; r < 4; ++r) {
                float v = acc[mt][r] + ob;
                if (INIT) hreg[nn][mt][r] = v; else hreg[nn][mt][r] += v;
            }
    }
}

// ---------------------------------------------------------------------------
// Row stats (mu, rsig) over the register-resident h. 2 internal syncs.
// ---------------------------------------------------------------------------
__device__ __forceinline__ void stats_pass(
    const float (&hreg)[2][3][4], float2* st,
    float (*rowS)[MROWS], float (*rowSS)[MROWS],
    int tid, int w, int c16, int q)
{
#pragma unroll
    for (int mt = 0; mt < 3; ++mt)
#pragma unroll
        for (int r = 0; r < 4; ++r) {
            float v0 = hreg[0][mt][r], v1 = hreg[1][mt][r];
            float s = v0 + v1, ss = v0 * v0 + v1 * v1;
#pragma unroll
            for (int off = 1; off < 16; off <<= 1) {
                s += __shfl_xor(s, off);
                ss += __shfl_xor(ss, off);
            }
            if (c16 == 0) {
                rowS[w][mt * 16 + q * 4 + r] = s;
                rowSS[w][mt * 16 + q * 4 + r] = ss;
            }
        }
    __syncthreads();
    if (tid < MROWS) {
        float s = 0.f, ss = 0.f;
#pragma unroll
        for (int i = 0; i < 8; ++i) { s += rowS[i][tid]; ss += rowSS[i][tid]; }
        float mu = s * (1.0f / D_);
        float var = ss * (1.0f / D_) - mu * mu;
        st[tid] = make_float2(mu, rsqrtf(var + EPS_));
    }
    __syncthreads();
}

// ---------------------------------------------------------------------------
// Mega-kernel: whole network. Grid 256 = 32 batches x 8 segments, 512 thr.
// ---------------------------------------------------------------------------
__global__ __launch_bounds__(512, 2) void k_mega(
    const float* __restrict__ x, const unsigned int* __restrict__ mask_w,
    const unsigned short* __restrict__ wt_in, const float* __restrict__ in_b,
    const float* __restrict__ ln_g, const float* __restrict__ ln_b,
    const float* __restrict__ dw_w, const float* __restrict__ dw_b,
    const unsigned short* __restrict__ wt_win, const float* __restrict__ win_b,
    const unsigned short* __restrict__ wt_wout, const float* __restrict__ wout_b,
    const float* __restrict__ fn_g, const float* __restrict__ fn_b,
    float* __restrict__ out0, float* __restrict__ out1)
{
    __shared__ unsigned short buf0[MROWS][ASTR];   // 25.3 KB
    __shared__ unsigned short buf1[MROWS][ASTR];   // 25.3 KB
    __shared__ float2 st[MROWS];
    __shared__ float rowS[8][MROWS];
    __shared__ float rowSS[8][MROWS];
    __shared__ int redL[8];
    __shared__ int lenS;

    int tid = threadIdx.x;
    int w = tid >> 6, lane = tid & 63;
    int c16 = lane & 15, q = lane >> 4;
    int bid = blockIdx.x;
    int b = bid >> 3, seg = bid & 7;
    int t0 = seg * 32 - 8;
    if (t0 < 0) t0 = 0;
    if (t0 > T_ - MROWS) t0 = T_ - MROWS;
    int out_lo = seg * 32;

    float hreg[2][3][4];

    // ---- length of batch b (with mask dtype detection, validated R1/R2) ----
    {
        int mode = 0;
        unsigned int w0 = mask_w[0];
        if (w0 == 0x3F800000u) mode = 2;
        else {
            bool u8 = false;
            for (int i = 0; i < 32; ++i) {
                if (mask_w[i * 1024] > 1u) { u8 = true; break; }
            }
            mode = u8 ? 1 : 0;
        }
        int s = 0;
        if (mode == 0) {
            const int* m = (const int*)mask_w;
            for (int i = tid; i < S_; i += 512) s += (m[(size_t)b * S_ + i] != 0);
        } else if (mode == 2) {
            const float* m = (const float*)mask_w;
            for (int i = tid; i < S_; i += 512) s += (m[(size_t)b * S_ + i] != 0.0f);
        } else {
            const unsigned char* m = (const unsigned char*)mask_w;
            for (int i = tid; i < S_; i += 512) s += (m[(size_t)b * S_ + i] != 0);
        }
#pragma unroll
        for (int off = 1; off < 64; off <<= 1) s += __shfl_xor(s, off);
        if (lane == 0) redL[w] = s;
        __syncthreads();
        if (tid == 0) {
            int tot = 0;
#pragma unroll
            for (int i = 0; i < 8; ++i) tot += redL[i];
            lenS = tot;
        }
        __syncthreads();
    }
    int L = lenS;

    // ---- compress -> buf0 (bf16) ----
    {
        int ccol = tid & 255, r0 = tid >> 8;
        float Lf = (float)L;
        float hi = fmaxf(Lf - 1.0f, 0.0f);
        int L1 = max(L - 1, 0);
        const float* xb = x + (size_t)b * S_ * DIN_ + ccol;
#pragma unroll
        for (int e = 0; e < 24; ++e) {
            int row = r0 + e * 2;
            int t = t0 + row;
            float src = ((float)t + 0.5f) * (Lf * (1.0f / T_)) - 0.5f;
            src = fminf(fmaxf(src, 0.0f), hi);
            int i0 = (int)floorf(src);
            int i1 = min(i0 + 1, L1);
            float wf = src - (float)i0;
            float v0 = xb[(size_t)i0 * DIN_];
            float v1 = xb[(size_t)i1 * DIN_];
            buf0[row][ccol] = f2bf((1.0f - wf) * v0 + wf * v1);
        }
    }
    __syncthreads();

    // ---- in-proj: h = xc @ in_w + in_b ----
    gemm_nk16<true>(buf0, wt_in, in_b, hreg, w, c16, q);

    // ---- 4 conv blocks ----
    for (int li = 0; li < NB_; ++li) {
        const float* g_i = ln_g + li * D_;
        const float* b_i = ln_b + li * D_;
        const float* dww = dw_w + li * D_ * K_;
        const float* dwb = dw_b + li * D_;
        const unsigned short* ww = wt_win + (size_t)li * 2 * D_ * D_;
        const float* wb = win_b + li * 2 * D_;
        const unsigned short* ow = wt_wout + (size_t)li * D_ * D_;
        const float* ob = wout_b + li * D_;

        // stats (also acts as barrier closing previous layer's buf0 reads)
        stats_pass(hreg, st, rowS, rowSS, tid, w, c16, q);

        // hn = LN(h) -> buf0 (bf16)
#pragma unroll
        for (int nn = 0; nn < 2; ++nn) {
            int col = (w + nn * 8) * 16 + c16;
            float gg = g_i[col], bb = b_i[col];
#pragma unroll
            for (int mt = 0; mt < 3; ++mt)
#pragma unroll
                for (int r = 0; r < 4; ++r) {
                    int row = mt * 16 + q * 4 + r;
                    float2 s = st[row];
                    buf0[row][col] = f2bf((hreg[nn][mt][r] - s.x) * s.y * gg + bb);
                }
        }
        __syncthreads();

        // depthwise conv buf0 -> buf1 (fp32 math, bf16 store)
        {
            int ccol = tid & 255, r0 = tid >> 8;
            float wk[K_];
#pragma unroll
            for (int k = 0; k < K_; ++k) wk[k] = dww[ccol * K_ + k];
            float cb = dwb[ccol];
#pragma unroll
            for (int e = 0; e < 24; ++e) {
                int row = r0 + e * 2;
                int t = t0 + row;
                float acc = cb;
#pragma unroll
                for (int k = 0; k < K_; ++k) {
                    int lr = row + k - 2, tt = t + k - 2;
                    if (lr >= 0 && lr < MROWS && tt >= 0 && tt < T_)
                        acc += bf2f(buf0[lr][ccol]) * wk[k];
                }
                buf1[row][ccol] = f2bf(acc);
            }
        }
        __syncthreads();

        // win GEMM (gate+val in-register) + act -> buf0 (bf16)
#pragma unroll
        for (int pp = 0; pp < 2; ++pp) {
            int p = w + pp * 8;
            const unsigned short* wg = ww + (size_t)(p * 16 + c16) * 256 + q * 8;
            const unsigned short* wv = wg + (size_t)256 * 256;
            floatx4 accg[3] = {}, accv[3] = {};
            shortx8 bg = *(const shortx8*)wg;
            shortx8 bv = *(const shortx8*)wv;
#pragma unroll
            for (int kk = 0; kk < 8; ++kk) {
                shortx8 bgn = bg, bvn = bv;
                if (kk < 7) {
                    bgn = *(const shortx8*)(wg + (kk + 1) * 32);
                    bvn = *(const shortx8*)(wv + (kk + 1) * 32);
                }
#pragma unroll
                for (int mt = 0; mt < 3; ++mt) {
                    shortx8 a = *(const shortx8*)&buf1[mt * 16 + c16][kk * 32 + q * 8];
                    accg[mt] = __builtin_amdgcn_mfma_f32_16x16x32_bf16(a, bg, accg[mt], 0, 0, 0);
                    accv[mt] = __builtin_amdgcn_mfma_f32_16x16x32_bf16(a, bv, accv[mt], 0, 0, 0);
                }
                bg = bgn; bv = bvn;
            }
            float biasg = wb[p * 16 + c16];
            float biasv = wb[256 + p * 16 + c16];
#pragma unroll
            for (int mt = 0; mt < 3; ++mt)
#pragma unroll
                for (int r = 0; r < 4; ++r) {
                    int row = mt * 16 + q * 4 + r;
                    float gate = accg[mt][r] + biasg;
                    float val  = accv[mt][r] + biasv;
                    float sg = 1.0f / (1.0f + expf(-gate));
                    float ge = 0.5f * val * (1.0f + erff(val * 0.70710678118654752f));
                    buf0[row][p * 16 + c16] = f2bf(sg * ge);
                }
        }
        __syncthreads();

        // wout GEMM: h += act @ wout + wout_b
        gemm_nk16<false>(buf0, ow, ob, hreg, w, c16, q);
    }

    // ---- final LN -> out0 ----
    stats_pass(hreg, st, rowS, rowSS, tid, w, c16, q);
#pragma unroll
    for (int nn = 0; nn < 2; ++nn) {
        int col = (w + nn * 8) * 16 + c16;
        float gg = fn_g[col], bb = fn_b[col];
#pragma unroll
        for (int mt = 0; mt < 3; ++mt)
#pragma unroll
            for (int r = 0; r < 4; ++r) {
                int row = mt * 16 + q * 4 + r;
                int t = t0 + row;
                int tl = t - out_lo;
                if (tl >= 0 && tl < 32) {
                    float2 s = st[row];
                    out0[((size_t)b * T_ + t) * D_ + col] =
                        (hreg[nn][mt][r] - s.x) * s.y * gg + bb;
                }
            }
    }
    if (tid < 32) out1[(size_t)b * T_ + out_lo + tid] = 1.0f;
}

// ---------------------------------------------------------------------------
extern "C" void kernel_launch(void* const* d_in, const int* in_sizes, int n_in,
                              void* d_out, int out_size, void* d_ws, size_t ws_size,
                              hipStream_t stream) {
    const float* x      = (const float*)d_in[0];
    const unsigned int* mask_w = (const unsigned int*)d_in[1];
    const float* in_w   = (const float*)d_in[2];
    const float* in_b   = (const float*)d_in[3];
    const float* ln_g   = (const float*)d_in[4];
    const float* ln_b   = (const float*)d_in[5];
    const float* dw_w   = (const float*)d_in[6];
    const float* dw_b   = (const float*)d_in[7];
    const float* win_w  = (const float*)d_in[8];
    const float* win_b  = (const float*)d_in[9];
    const float* wout_w = (const float*)d_in[10];
    const float* wout_b = (const float*)d_in[11];
    const float* fn_g   = (const float*)d_in[12];
    const float* fn_b   = (const float*)d_in[13];

    char* w8 = (char*)d_ws;
    unsigned short* wt_in   = (unsigned short*)w8;                 // 128 KB
    unsigned short* wt_win  = wt_in  + (size_t)D_ * DIN_;          // 1 MB
    unsigned short* wt_wout = wt_win + (size_t)NB_ * 2 * D_ * D_;  // 512 KB

    float* out0 = (float*)d_out;
    float* out1 = out0 + (size_t)ROWS_ * D_;

    k_wt<<<dim3(16, 8, 9), 256, 0, stream>>>(in_w, win_w, wout_w, wt_in, wt_win, wt_wout);
    k_mega<<<256, 512, 0, stream>>>(x, mask_w, wt_in, in_b, ln_g, ln_b, dw_w, dw_b,
                                    wt_win, win_b, wt_wout, wout_b, fn_g, fn_b,
                                    out0, out1);
}